// Round 13
// baseline (1095.483 us; speedup 1.0000x reference)
//
#include <hip/hip_runtime.h>
#include <hip/hip_bf16.h>
#include <stdint.h>
#include <math.h>

// ---------------------------------------------------------------------------
// SymmetricRBM: CD loss, 10-step Gibbs, JAX-threefry-exact RNG.
// B=8192, V=H=1024. R28->R29: B operand direct from global (no Bs LDS).
//  - Budget at 40us steady: LDS pipe ~15us is the largest consumer (72KB/
//    block-iter). W is stationary + L2-resident per XCD (T1). Its fragment
//    is 16 CONTIGUOUS bytes/lane -> global_load_dwordx4 direct, issued at
//    iter start (~600cyc before use, L2-hit ~200cyc). Deletes 8KB writes +
//    16KB reads LDS per block-iter (-33% LDS traffic); LDS 24->16KB/block.
//  - Unlike R23: only B is direct; A keeps coalesced gload_lds staging and
//    the barriers remain. B loads have no LDS dependency -> scheduler-free.
//  - Everything else identical to R28 (T1 placement, 128x64, 4 blk/CU,
//    in-loop RNG, DPP red16, setprio). Numerics bit-identical.
// ---------------------------------------------------------------------------

static constexpr int Bn = 8192;
static constexpr int Vn = 1024;
static constexpr int Hn = 1024;
static constexpr int KSTEPS = 10;

typedef _Float16 f16;
typedef f16   f16x4 __attribute__((ext_vector_type(4)));
typedef f16   f16x8 __attribute__((ext_vector_type(8)));
typedef float f32x4 __attribute__((ext_vector_type(4)));

#define GLOBAL_LOAD_LDS16(g, l)                                              \
  __builtin_amdgcn_global_load_lds(                                          \
      (const __attribute__((address_space(1))) uint32_t*)(g),                \
      (__attribute__((address_space(3))) uint32_t*)(l), 16, 0, 0)

// ------------------------- Threefry-2x32 (JAX-exact) -----------------------
__device__ __forceinline__ uint32_t rotl32(uint32_t x, int d) {
  return __builtin_amdgcn_alignbit(x, x, 32 - d);
}

__device__ __forceinline__ void tf2x32(uint32_t k0, uint32_t k1,
                                       uint32_t x0, uint32_t x1,
                                       uint32_t& o0, uint32_t& o1) {
  uint32_t k2 = k0 ^ k1 ^ 0x1BD11BDAu;
#define TFR(r) { x0 += x1; x1 = rotl32(x1, (r)); x1 ^= x0; }
  x0 += k0; x1 += k1;
  TFR(13) TFR(15) TFR(26) TFR(6)
  x0 += k1; x1 += k2 + 1u;
  TFR(17) TFR(29) TFR(16) TFR(24)
  x0 += k2; x1 += k0 + 2u;
  TFR(13) TFR(15) TFR(26) TFR(6)
  x0 += k0; x1 += k1 + 3u;
  TFR(17) TFR(29) TFR(16) TFR(24)
  x0 += k1; x1 += k2 + 4u;
  TFR(13) TFR(15) TFR(26) TFR(6)
  x0 += k2; x1 += k0 + 5u;
#undef TFR
  o0 = x0; o1 = x1;
}

__device__ __forceinline__ float rng_u01(uint2 key, uint32_t idx) {
  uint32_t o0, o1;
  tf2x32(key.x, key.y, 0u, idx, o0, o1);
  uint32_t bits = o0 ^ o1;
  return __uint_as_float((bits >> 9) | 0x3F800000u) - 1.0f;
}

// 2-wide noinline variant: one code copy (I-cache), called from the unrolled
// K-loop so threefry VALU executes while global_load_lds is in flight.
__device__ __attribute__((noinline)) float2 rng2_u01(uint2 key, uint32_t i0,
                                                     uint32_t i1) {
  float2 r;
  r.x = rng_u01(key, i0);
  r.y = rng_u01(key, i1);
  return r;
}

// fast Bernoulli accept: r01 < sigmoid(z)  <=>  r01*(1+exp(-z)) < 1
__device__ __forceinline__ float bern_fast(float z, float r01) {
  float e = __expf(-z);
  return (__builtin_fmaf(r01, e, r01) < 1.0f) ? 1.f : 0.f;
}
__device__ __forceinline__ float softplus_fast(float x) {
  return fmaxf(x, 0.f) + __logf(1.f + __expf(-fabsf(x)));
}

// --------------- DPP 16-lane sum (VALU-only, bit-identical) ----------------
template <int CTRL>
__device__ __forceinline__ float dpp_add16(float v) {
  int x = __builtin_amdgcn_update_dpp(0, __float_as_int(v), CTRL, 0xF, 0xF, true);
  return v + __int_as_float(x);
}
__device__ __forceinline__ float red16(float v) {
  v = dpp_add16<0xB1>(v);    // quad_perm(1,0,3,2)  == xor 1
  v = dpp_add16<0x4E>(v);    // quad_perm(2,3,0,1)  == xor 2
  v = dpp_add16<0x141>(v);   // row_half_mirror     == xor 4 (same value)
  v = dpp_add16<0x140>(v);   // row_mirror          == xor 8 (same value)
  return v;
}

// ------------------------------- prep kernels ------------------------------
__global__ void prep_keys(const int* __restrict__ seedp, uint2* __restrict__ keys) {
  if (threadIdx.x != 0 || blockIdx.x != 0) return;
  uint32_t seed = (uint32_t)(*seedp);
  uint2 key = make_uint2(0u, seed);
  uint2 nk, kk;
  tf2x32(key.x, key.y, 0u, 0u, nk.x, nk.y);
  tf2x32(key.x, key.y, 0u, 1u, kk.x, kk.y);
  keys[0] = kk;   // k0
  key = nk;
  for (int s = 0; s < KSTEPS; ++s) {
    uint2 t0, t1, t2, t3;
    tf2x32(key.x, key.y, 0u, 0u, t0.x, t0.y);
    tf2x32(key.x, key.y, 0u, 1u, t1.x, t1.y);
    tf2x32(key.x, key.y, 0u, 2u, t2.x, t2.y);
    tf2x32(key.x, key.y, 0u, 3u, t3.x, t3.y);
    key = t0;
    keys[1 + 3*s] = t1;  // k1
    keys[2 + 3*s] = t2;  // k2
    keys[3 + 3*s] = t3;  // k3
  }
}

__global__ __launch_bounds__(256) void colsum_part(
    const float* __restrict__ W, float* __restrict__ part) {
  const int bx = blockIdx.x, t = threadIdx.x;
  float s0 = 0.f, s1 = 0.f, s2 = 0.f, s3 = 0.f;
#pragma unroll
  for (int r = 0; r < 16; ++r) {
    const float* row = W + (size_t)(bx * 16 + r) * Hn;
    s0 += row[t]; s1 += row[t + 256]; s2 += row[t + 512]; s3 += row[t + 768];
  }
  float* p = part + (size_t)bx * Hn;
  p[t] = s0; p[t + 256] = s1; p[t + 512] = s2; p[t + 768] = s3;
}

__global__ __launch_bounds__(256) void colsum_red(
    const float* __restrict__ part, float* __restrict__ cs) {
  const int col = blockIdx.x * 256 + threadIdx.x;
  float s = 0.f;
#pragma unroll
  for (int k = 0; k < 64; ++k) s += part[(size_t)k * Hn + col];
  cs[col] = s;
}

__global__ void bsum_k(const float* __restrict__ bvec, float* __restrict__ bs) {
  __shared__ float sb[4];
  float s = 0.f;
  for (int i = threadIdx.x; i < Vn; i += 256) s += bvec[i];
  for (int off = 32; off > 0; off >>= 1) s += __shfl_down(s, off, 64);
  int wv = threadIdx.x >> 6, ln = threadIdx.x & 63;
  if (ln == 0) sb[wv] = s;
  __syncthreads();
  if (threadIdx.x == 0) bs[0] = sb[0] + sb[1] + sb[2] + sb[3];
}

__global__ __launch_bounds__(256) void cast_W(
    const float* __restrict__ W, f16* __restrict__ Wf, f16* __restrict__ WTf) {
  __shared__ f16 tile[64][65];
  const int j0 = blockIdx.x * 64, i0 = blockIdx.y * 64;
  const int tx = threadIdx.x & 63, tg = threadIdx.x >> 6;
#pragma unroll 4
  for (int rr = 0; rr < 16; ++rr) {
    const int row = tg * 16 + rr;
    float w = W[(size_t)(i0 + row) * Hn + j0 + tx];
    f16 hw = (f16)w;
    Wf[(size_t)(i0 + row) * Hn + j0 + tx] = hw;
    tile[row][tx] = hw;
  }
  __syncthreads();
#pragma unroll 4
  for (int rr = 0; rr < 16; ++rr) {
    const int row = tg * 16 + rr;
    WTf[(size_t)(j0 + row) * Vn + i0 + tx] = tile[tx][row];
  }
}

__global__ void u0_init(const uint2* __restrict__ keys, float* __restrict__ u0) {
  int b = blockIdx.x * 256 + threadIdx.x;
  float r01 = rng_u01(keys[0], (uint32_t)b);
  u0[b] = (r01 < 0.5f) ? 1.f : 0.f;
}

// x0 = u0 ? v_data : 1-v_data; also emit pXB[0][row][slot] = Sum x0*b (32 cols)
__global__ __launch_bounds__(256) void cast_vx(
    const float* __restrict__ vd, const float* __restrict__ u0,
    const float* __restrict__ bvec, f16* __restrict__ x,
    float* __restrict__ pXB0) {
  const int row = blockIdx.x;                       // 1 row per block
  const int t = threadIdx.x;                        // cols 4t..4t+3
  const float uo = u0[row];
  const float4 d  = ((const float4*)(vd + (size_t)row * Vn))[t];
  const float4 bv = ((const float4*)bvec)[t];
  float xv[4] = { d.x, d.y, d.z, d.w };
  if (uo <= 0.5f) { xv[0]=1.f-xv[0]; xv[1]=1.f-xv[1]; xv[2]=1.f-xv[2]; xv[3]=1.f-xv[3]; }
  f16x4 o = { (f16)xv[0], (f16)xv[1], (f16)xv[2], (f16)xv[3] };
  *(f16x4*)(x + (size_t)row * Vn + t * 4) = o;
  float xb = xv[0]*bv.x + xv[1]*bv.y + xv[2]*bv.z + xv[3]*bv.w;
#pragma unroll
  for (int m = 1; m < 8; m <<= 1) xb += __shfl_xor(xb, m, 64);
  if ((t & 7) == 0) pXB0[(size_t)row * 32 + (t >> 3)] = xb;
}

// ------ GEMM: 128x64 tile, 4 blk/CU, XCD-placed, A-LDS + B-direct ----------
// Tile remap (T1): L=by*64+bx; xcd=L&7, s=L>>3 -> bxp=xcd*8+s/16, byp=s&15.
// 4 waves in 2x2 grid; each wave owns 64x32 via acc[4][2] of 16x16x32.
// Per K-step: stage A (4 gload_lds), issue 4 direct B loads (W is L2-hot,
// fragment = 16 contiguous B/lane), threefry 2 samples, sync,
// [setprio(1)] ds_read A + MFMA [setprio(0)], sync.
// Each wave covers exactly one 32-col slot: slot = byp*2 + (wave&1).
// EPI 1: h=Bern(sig(M+c)); pA = Sum h*colsum, pXA = Sum h*M per slot.
// EPI 2: EPI1 + free-energy partials SA = Sum sp(M+c), SB = Sum sp(cs-M+c).
// EPI 3: x_new=Bern(sig(C+b)); pXBn = Sum x_new*b per slot.
// EPI 4: SA/SB partials only (no RNG).
template <int EPI>
__global__ __launch_bounds__(256, 4) void gemm_s(
    const f16* __restrict__ A, const f16* __restrict__ Bm,
    f16* __restrict__ outH, f16* __restrict__ xnew,
    const float* __restrict__ bvec, const float* __restrict__ cvec,
    const float* __restrict__ colsum,
    float* __restrict__ pA, float* __restrict__ pXA, float* __restrict__ pXBn,
    float* __restrict__ pSA, float* __restrict__ pSB,
    const uint2* __restrict__ keys, int keyIdx)
{
  constexpr int N = 1024, K = 1024, BK = 64;
  __shared__ alignas(16) f16 As[128 * BK];   // 16 KB (A only)

  const int t = threadIdx.x, wave = t >> 6, lane = t & 63;
  const int l15 = lane & 15, quad = lane >> 4;

  // T1 placement: bijective (bx,by) remap grouping A-panels per XCD
  const int L   = blockIdx.y * 64 + blockIdx.x;
  const int xcd = L & 7, sl = L >> 3;
  const int bxp = xcd * 8 + (sl >> 4);
  const int byp = sl & 15;
  const int m0 = bxp * 128, n0 = byp * 64;
  const int wm = (wave >> 1) * 64, wn = (wave & 1) * 32;

  const int rbase = lane >> 3;                 // row within an 8-row group
  const int gch   = (lane & 7) ^ rbase;        // pre-swizzled source chunk
  const f16* gA = A + (size_t)(m0 + wave * 32 + rbase) * K + gch * 8;
  f16* lA = As + wave * 32 * BK;

  // direct-B fragment base pointers (16 contiguous bytes per lane)
  const f16* pb[2];
#pragma unroll
  for (int i = 0; i < 2; ++i)
    pb[i] = Bm + (size_t)(n0 + wn + i * 16 + l15) * K + quad * 8;

  const int swz = l15 & 7;
  const int oA  = (wm + l15) * BK;

  uint2 key = make_uint2(0u, 0u);
  if constexpr (EPI != 4) key = keys[keyIdx];

  f32x4 acc[4][2] = {};
  float r01v[32];

#pragma unroll
  for (int ki = 0; ki < 16; ++ki) {
    const int k0 = ki * 64;
    // 1) stage A K-tile (issue only; drained by the coming barrier)
#pragma unroll
    for (int i = 0; i < 4; ++i)
      GLOBAL_LOAD_LDS16(gA + k0 + i * 8 * K, lA + i * 8 * BK);
    // 2) issue direct B loads (L2-hot W; ~600cyc before first use)
    f16x8 bf[2][2];
#pragma unroll
    for (int kc = 0; kc < 2; ++kc)
#pragma unroll
      for (int i = 0; i < 2; ++i)
        bf[kc][i] = *(const f16x8*)(pb[i] + k0 + kc * 32);
    // 3) threefry for elements 2ki, 2ki+1 while loads fly
    if constexpr (EPI != 4) {
      uint32_t idx[2];
#pragma unroll
      for (int j = 0; j < 2; ++j) {
        const int e  = ki * 2 + j;                  // e = mt*8 + r*2 + nt
        const int mt = e >> 3, r = (e >> 1) & 3, nt = e & 1;
        const int gm = m0 + wm + mt * 16 + quad * 4 + r;
        const int gn = n0 + wn + nt * 16 + l15;
        idx[j] = (uint32_t)(gm * N + gn);
      }
      float2 rv = rng2_u01(key, idx[0], idx[1]);
      r01v[ki * 2 + 0] = rv.x;
      r01v[ki * 2 + 1] = rv.y;
    }
    __syncthreads();
    // 4) compute: A from LDS, B from registers
    __builtin_amdgcn_s_setprio(1);
#pragma unroll
    for (int kc = 0; kc < 2; ++kc) {
      const int fc = ((kc * 4 + quad) ^ swz) * 8;
      f16x8 af[4];
#pragma unroll
      for (int i = 0; i < 4; ++i)
        af[i] = *(const f16x8*)(&As[oA + i * 16 * BK + fc]);
#pragma unroll
      for (int mt = 0; mt < 4; ++mt)
#pragma unroll
        for (int nt = 0; nt < 2; ++nt)
          acc[mt][nt] = __builtin_amdgcn_mfma_f32_16x16x32_f16(af[mt], bf[kc][nt], acc[mt][nt], 0, 0, 0);
    }
    __builtin_amdgcn_s_setprio(0);
    if (ki < 15) __syncthreads();
  }

  // epilogue: C/D layout col = lane&15, row = quad*4 + reg   (m89/m91)
  // each wave covers one 32-col slot
  const int slot = byp * 2 + (wave & 1);

  if constexpr (EPI == 1 || EPI == 2) {
    float csv[2], cvv[2];
#pragma unroll
    for (int nt = 0; nt < 2; ++nt) {
      const int gn = n0 + wn + nt * 16 + l15;
      csv[nt] = colsum[gn];
      cvv[nt] = cvec[gn];
    }
#pragma unroll
    for (int mt = 0; mt < 4; ++mt)
#pragma unroll
      for (int r = 0; r < 4; ++r) {
        const int gm = m0 + wm + mt * 16 + quad * 4 + r;
        float pa = 0.f, pxa = 0.f, sa = 0.f, sb = 0.f;
#pragma unroll
        for (int nt = 0; nt < 2; ++nt) {
          const int gn = n0 + wn + nt * 16 + l15;
          const float val = acc[mt][nt][r];            // M = x@W
          const float r01 = r01v[mt * 8 + r * 2 + nt];
          float hq  = bern_fast(val + cvv[nt], r01);
          outH[(size_t)gm * N + gn] = (f16)hq;
          pa  += hq * csv[nt];
          pxa += hq * val;
          if constexpr (EPI == 2) {
            sa += softplus_fast(val + cvv[nt]);
            sb += softplus_fast(csv[nt] - val + cvv[nt]);
          }
        }
        pa  = red16(pa);
        pxa = red16(pxa);
        if constexpr (EPI == 2) {
          sa = red16(sa);
          sb = red16(sb);
        }
        if (l15 == 0) {
          pA [(size_t)gm * 32 + slot] = pa;
          pXA[(size_t)gm * 32 + slot] = pxa;
          if constexpr (EPI == 2) {
            pSA[(size_t)gm * 32 + slot] = sa;
            pSB[(size_t)gm * 32 + slot] = sb;
          }
        }
      }
  } else if constexpr (EPI == 3) {
    float bb[2];
#pragma unroll
    for (int nt = 0; nt < 2; ++nt) bb[nt] = bvec[n0 + wn + nt * 16 + l15];
#pragma unroll
    for (int mt = 0; mt < 4; ++mt)
#pragma unroll
      for (int r = 0; r < 4; ++r) {
        const int gm = m0 + wm + mt * 16 + quad * 4 + r;
        float pxb = 0.f;
#pragma unroll
        for (int nt = 0; nt < 2; ++nt) {
          const int gn = n0 + wn + nt * 16 + l15;
          const float aval = acc[mt][nt][r];
          const float r01 = r01v[mt * 8 + r * 2 + nt];
          float xq  = bern_fast(aval + bb[nt], r01);
          xnew[(size_t)gm * N + gn] = (f16)xq;
          pxb += xq * bb[nt];
        }
        pxb = red16(pxb);
        if (l15 == 0) pXBn[(size_t)gm * 32 + slot] = pxb;
      }
  } else {
    // EPI 4: free-energy partials only
    float csv[2], cvv[2];
#pragma unroll
    for (int nt = 0; nt < 2; ++nt) {
      const int gn = n0 + wn + nt * 16 + l15;
      csv[nt] = colsum[gn];
      cvv[nt] = cvec[gn];
    }
#pragma unroll
    for (int mt = 0; mt < 4; ++mt)
#pragma unroll
      for (int r = 0; r < 4; ++r) {
        const int gm = m0 + wm + mt * 16 + quad * 4 + r;
        float sa = 0.f, sb = 0.f;
#pragma unroll
        for (int nt = 0; nt < 2; ++nt) {
          const float val = acc[mt][nt][r];
          sa += softplus_fast(val + cvv[nt]);
          sb += softplus_fast(csv[nt] - val + cvv[nt]);
        }
        sa = red16(sa);
        sb = red16(sb);
        if (l15 == 0) {
          pSA[(size_t)gm * 32 + slot] = sa;
          pSB[(size_t)gm * 32 + slot] = sb;
        }
      }
  }
}

// -------- deferred u-recurrence: half-wave per row, coalesced reads ---------
__global__ __launch_bounds__(256) void u_chain(
    const float* __restrict__ pA, const float* __restrict__ pXA,
    const float* __restrict__ pXB, const float* __restrict__ bsum,
    const uint2* __restrict__ keys, const float* __restrict__ u0,
    float* __restrict__ uF)
{
  const int t = threadIdx.x, wave = t >> 6, lane = t & 63;
  const int r2 = lane >> 5, slot = lane & 31;
  const int row = blockIdx.x * 8 + wave * 2 + r2;
  const float bs = bsum[0];
  float uo = u0[row];
  for (int s = 0; s < KSTEPS; ++s) {
    const size_t o = (size_t)s * 32 * Bn + (size_t)row * 32 + slot;
    float sa  = pA [o];
    float sxa = pXA[o];
    float sxb = pXB[o];
#pragma unroll
    for (int m = 1; m < 32; m <<= 1) {
      sa  += __shfl_xor(sa,  m, 64);
      sxa += __shfl_xor(sxa, m, 64);
      sxb += __shfl_xor(sxb, m, 64);
    }
    const float va = (uo > 0.5f) ? sxa : sa - sxa;
    const float vb = (uo > 0.5f) ? sxb : bs - sxb;
    const float dE = -bs - sa + 2.f * vb + 2.f * va;
    uo = bern_fast(dE, rng_u01(keys[2 + 3 * s], (uint32_t)row));
  }
  if (slot == 0) uF[row] = uo;
}

// ---------------- fused free energy finish (Fd and Fm) ----------------------
__device__ __forceinline__ float fe_eval(float SA, float SB, float xb,
                                         float uo, float bs) {
  float S1 = (uo > 0.5f) ? SA : SB;
  float S2 = (uo > 0.5f) ? SB : SA;
  float vb = (uo > 0.5f) ? xb : bs - xb;
  float negn = vb - S1;
  float negf = (bs - vb) - S2;
  float mx = fmaxf(negn, negf);
  return -(mx + logf(expf(negn - mx) + expf(negf - mx)));
}

__global__ __launch_bounds__(256) void fe_finish(
    const float* __restrict__ SA0, const float* __restrict__ SB0,
    const float* __restrict__ xb0,
    const float* __restrict__ SAF, const float* __restrict__ SBF,
    const float* __restrict__ xbF,
    const float* __restrict__ u0, const float* __restrict__ uF,
    const float* __restrict__ bsum,
    float* __restrict__ Fd, float* __restrict__ Fm)
{
  const int t = threadIdx.x, wave = t >> 6, lane = t & 63;
  const int r2 = lane >> 5, slot = lane & 31;
  const int row = blockIdx.x * 8 + wave * 2 + r2;
  const size_t o = (size_t)row * 32 + slot;
  const float bs = bsum[0];
  float a0 = SA0[o], b0 = SB0[o], x0 = xb0[o];
  float aF = SAF[o], bF = SBF[o], xF = xbF[o];
#pragma unroll
  for (int m = 1; m < 32; m <<= 1) {
    a0 += __shfl_xor(a0, m, 64);  b0 += __shfl_xor(b0, m, 64);
    x0 += __shfl_xor(x0, m, 64);  aF += __shfl_xor(aF, m, 64);
    bF += __shfl_xor(bF, m, 64);  xF += __shfl_xor(xF, m, 64);
  }
  if (slot == 0) {
    Fd[row] = fe_eval(a0, b0, x0, u0[row], bs);
    Fm[row] = fe_eval(aF, bF, xF, uF[row], bs);
  }
}

__global__ __launch_bounds__(256) void finalize_k(
    const float* __restrict__ Fd, const float* __restrict__ Fm, float* __restrict__ out)
{
  __shared__ double sb[8];
  double sd = 0.0, sm = 0.0;
  for (int i = threadIdx.x; i < Bn; i += 256) { sd += (double)Fd[i]; sm += (double)Fm[i]; }
  for (int off = 32; off > 0; off >>= 1) { sd += __shfl_down(sd, off, 64); sm += __shfl_down(sm, off, 64); }
  const int wv = threadIdx.x >> 6, ln = threadIdx.x & 63;
  if (ln == 0) { sb[wv] = sd; sb[4 + wv] = sm; }
  __syncthreads();
  if (threadIdx.x == 0) {
    sd = sb[0] + sb[1] + sb[2] + sb[3];
    sm = sb[4] + sb[5] + sb[6] + sb[7];
    out[0] = (float)((sd - sm) / (double)Bn);
  }
}

// ------------------------------ launch glue --------------------------------
extern "C" void kernel_launch(void* const* d_in, const int* in_sizes, int n_in,
                              void* d_out, int out_size, void* d_ws, size_t ws_size,
                              hipStream_t stream) {
  const float* v_data = (const float*)d_in[0];
  const float* W      = (const float*)d_in[1];
  const float* bvec   = (const float*)d_in[2];
  const float* cvec   = (const float*)d_in[3];
  const int*   seedp  = (const int*)d_in[4];
  float* out = (float*)d_out;

  char* ws = (char*)d_ws;
  size_t off = 0;
  auto alloc = [&](size_t bytes) -> void* {
    void* p = ws + off;
    off += (bytes + 255) & ~(size_t)255;
    return p;
  };
  f16*   xb0  = (f16*)alloc((size_t)Bn * Vn * 2);     // 16 MB x ping
  f16*   xb1  = (f16*)alloc((size_t)Bn * Vn * 2);     // 16 MB x pong
  f16*   h    = (f16*)alloc((size_t)Bn * Hn * 2);     // 16 MB
  f16*   Wf   = (f16*)alloc((size_t)Vn * Hn * 2);     // 2 MB  [V][H]
  f16*   WTf  = (f16*)alloc((size_t)Vn * Hn * 2);     // 2 MB  [H][V]
  float* cpart  = (float*)alloc(64 * Hn * 4);
  float* colsum = (float*)alloc(Hn * 4);
  float* bsum   = (float*)alloc(256);
  uint2* keys   = (uint2*)alloc(64 * sizeof(uint2));
  float* u0     = (float*)alloc(Bn * 4);
  float* uF     = (float*)alloc(Bn * 4);
  float* pA     = (float*)alloc((size_t)KSTEPS * 32 * Bn * 4);        // 10 MB
  float* pXA    = (float*)alloc((size_t)KSTEPS * 32 * Bn * 4);        // 10 MB
  float* pXB    = (float*)alloc((size_t)(KSTEPS + 1) * 32 * Bn * 4);  // 11 MB
  float* SA0    = (float*)alloc((size_t)32 * Bn * 4);                 // 1 MB
  float* SB0    = (float*)alloc((size_t)32 * Bn * 4);
  float* SAF    = (float*)alloc((size_t)32 * Bn * 4);
  float* SBF    = (float*)alloc((size_t)32 * Bn * 4);
  float* Fd     = (float*)alloc(Bn * 4);
  float* Fm     = (float*)alloc(Bn * 4);
  (void)ws_size; (void)in_sizes; (void)n_in; (void)out_size;

  prep_keys<<<1, 64, 0, stream>>>(seedp, keys);
  colsum_part<<<64, 256, 0, stream>>>(W, cpart);
  colsum_red<<<4, 256, 0, stream>>>(cpart, colsum);
  bsum_k<<<1, 256, 0, stream>>>(bvec, bsum);
  cast_W<<<dim3(Hn / 64, Vn / 64), 256, 0, stream>>>(W, Wf, WTf);
  u0_init<<<Bn / 256, 256, 0, stream>>>(keys, u0);
  cast_vx<<<Bn, 256, 0, stream>>>(v_data, u0, bvec, xb0, pXB);   // pXB slab 0

  dim3 gg(Bn / 128, Hn / 64);   // 1024 blocks = 4/CU (tile remapped in-kernel)
  f16* xs[2] = { xb0, xb1 };
  const size_t SL = (size_t)32 * Bn;

  for (int s = 0; s < KSTEPS; ++s) {
    // M = x_s@W -> h sampled; pA/pXA slab s; step 0 also emits SA0/SB0 (Fd)
    if (s == 0) {
      gemm_s<2><<<gg, 256, 0, stream>>>(xs[0], WTf, h, nullptr, nullptr, cvec,
                                        colsum, pA, pXA, nullptr, SA0, SB0,
                                        keys, 1);
    } else {
      gemm_s<1><<<gg, 256, 0, stream>>>(xs[s & 1], WTf, h, nullptr, nullptr, cvec,
                                        colsum, pA + (size_t)s * SL,
                                        pXA + (size_t)s * SL, nullptr,
                                        nullptr, nullptr, keys, 1 + 3 * s);
    }
    // a = h@W^T -> x_{s+1} sampled; pXB slab s+1
    gemm_s<3><<<gg, 256, 0, stream>>>(h, Wf, nullptr, xs[(s + 1) & 1], bvec,
                                      nullptr, nullptr, nullptr, nullptr,
                                      pXB + (size_t)(s + 1) * SL,
                                      nullptr, nullptr, keys, 3 + 3 * s);
  }

  // F(v_model) partials: M = x10@W -> SAF/SBF
  gemm_s<4><<<gg, 256, 0, stream>>>(xs[KSTEPS & 1], WTf, nullptr, nullptr,
                                    nullptr, cvec, colsum, nullptr, nullptr,
                                    nullptr, SAF, SBF, keys, 0);

  u_chain<<<Bn / 8, 256, 0, stream>>>(pA, pXA, pXB, bsum, keys, u0, uF);
  fe_finish<<<Bn / 8, 256, 0, stream>>>(SA0, SB0, pXB,
                                        SAF, SBF, pXB + (size_t)KSTEPS * SL,
                                        u0, uF, bsum, Fd, Fm);
  finalize_k<<<1, 256, 0, stream>>>(Fd, Fm, out);
}

// Round 14
// 786.030 us; speedup vs baseline: 1.3937x; 1.3937x over previous
//
#include <hip/hip_runtime.h>
#include <hip/hip_bf16.h>
#include <stdint.h>
#include <math.h>

// ---------------------------------------------------------------------------
// SymmetricRBM: CD loss, 10-step Gibbs, JAX-threefry-exact RNG.
// B=8192, V=H=1024. R30 = R28 (best, 847us) + inlined rng (drop noinline).
//  - R29 (direct-B) regressed 2x-confirmed scatter lesson: per-lane
//    row-strided global fragments fragment into 16 segments/inst. Reverted.
//  - Last micro-lever: R19's __noinline__ rng wrapper (I-cache motivated at
//    4 samples/iter) now walls threefry off from the gload_lds shadow and
//    adds call overhead. At 2 samples/iter inlining is ~9KB code.
//  - Everything else identical to R28 (T1 placement, 128x64, 4 blk/CU,
//    A-LDS staging, in-loop RNG, DPP red16, setprio). Numerics identical.
// ---------------------------------------------------------------------------

static constexpr int Bn = 8192;
static constexpr int Vn = 1024;
static constexpr int Hn = 1024;
static constexpr int KSTEPS = 10;

typedef _Float16 f16;
typedef f16   f16x4 __attribute__((ext_vector_type(4)));
typedef f16   f16x8 __attribute__((ext_vector_type(8)));
typedef float f32x4 __attribute__((ext_vector_type(4)));

#define GLOBAL_LOAD_LDS16(g, l)                                              \
  __builtin_amdgcn_global_load_lds(                                          \
      (const __attribute__((address_space(1))) uint32_t*)(g),                \
      (__attribute__((address_space(3))) uint32_t*)(l), 16, 0, 0)

// ------------------------- Threefry-2x32 (JAX-exact) -----------------------
__device__ __forceinline__ uint32_t rotl32(uint32_t x, int d) {
  return __builtin_amdgcn_alignbit(x, x, 32 - d);
}

__device__ __forceinline__ void tf2x32(uint32_t k0, uint32_t k1,
                                       uint32_t x0, uint32_t x1,
                                       uint32_t& o0, uint32_t& o1) {
  uint32_t k2 = k0 ^ k1 ^ 0x1BD11BDAu;
#define TFR(r) { x0 += x1; x1 = rotl32(x1, (r)); x1 ^= x0; }
  x0 += k0; x1 += k1;
  TFR(13) TFR(15) TFR(26) TFR(6)
  x0 += k1; x1 += k2 + 1u;
  TFR(17) TFR(29) TFR(16) TFR(24)
  x0 += k2; x1 += k0 + 2u;
  TFR(13) TFR(15) TFR(26) TFR(6)
  x0 += k0; x1 += k1 + 3u;
  TFR(17) TFR(29) TFR(16) TFR(24)
  x0 += k1; x1 += k2 + 4u;
  TFR(13) TFR(15) TFR(26) TFR(6)
  x0 += k2; x1 += k0 + 5u;
#undef TFR
  o0 = x0; o1 = x1;
}

__device__ __forceinline__ float rng_u01(uint2 key, uint32_t idx) {
  uint32_t o0, o1;
  tf2x32(key.x, key.y, 0u, idx, o0, o1);
  uint32_t bits = o0 ^ o1;
  return __uint_as_float((bits >> 9) | 0x3F800000u) - 1.0f;
}

// 2-wide INLINED variant: scheduler can interleave threefry with in-flight
// global_load_lds (no call boundary).
__device__ __forceinline__ float2 rng2_u01(uint2 key, uint32_t i0,
                                           uint32_t i1) {
  float2 r;
  r.x = rng_u01(key, i0);
  r.y = rng_u01(key, i1);
  return r;
}

// fast Bernoulli accept: r01 < sigmoid(z)  <=>  r01*(1+exp(-z)) < 1
__device__ __forceinline__ float bern_fast(float z, float r01) {
  float e = __expf(-z);
  return (__builtin_fmaf(r01, e, r01) < 1.0f) ? 1.f : 0.f;
}
__device__ __forceinline__ float softplus_fast(float x) {
  return fmaxf(x, 0.f) + __logf(1.f + __expf(-fabsf(x)));
}

// --------------- DPP 16-lane sum (VALU-only, bit-identical) ----------------
template <int CTRL>
__device__ __forceinline__ float dpp_add16(float v) {
  int x = __builtin_amdgcn_update_dpp(0, __float_as_int(v), CTRL, 0xF, 0xF, true);
  return v + __int_as_float(x);
}
__device__ __forceinline__ float red16(float v) {
  v = dpp_add16<0xB1>(v);    // quad_perm(1,0,3,2)  == xor 1
  v = dpp_add16<0x4E>(v);    // quad_perm(2,3,0,1)  == xor 2
  v = dpp_add16<0x141>(v);   // row_half_mirror     == xor 4 (same value)
  v = dpp_add16<0x140>(v);   // row_mirror          == xor 8 (same value)
  return v;
}

// ------------------------------- prep kernels ------------------------------
__global__ void prep_keys(const int* __restrict__ seedp, uint2* __restrict__ keys) {
  if (threadIdx.x != 0 || blockIdx.x != 0) return;
  uint32_t seed = (uint32_t)(*seedp);
  uint2 key = make_uint2(0u, seed);
  uint2 nk, kk;
  tf2x32(key.x, key.y, 0u, 0u, nk.x, nk.y);
  tf2x32(key.x, key.y, 0u, 1u, kk.x, kk.y);
  keys[0] = kk;   // k0
  key = nk;
  for (int s = 0; s < KSTEPS; ++s) {
    uint2 t0, t1, t2, t3;
    tf2x32(key.x, key.y, 0u, 0u, t0.x, t0.y);
    tf2x32(key.x, key.y, 0u, 1u, t1.x, t1.y);
    tf2x32(key.x, key.y, 0u, 2u, t2.x, t2.y);
    tf2x32(key.x, key.y, 0u, 3u, t3.x, t3.y);
    key = t0;
    keys[1 + 3*s] = t1;  // k1
    keys[2 + 3*s] = t2;  // k2
    keys[3 + 3*s] = t3;  // k3
  }
}

__global__ __launch_bounds__(256) void colsum_part(
    const float* __restrict__ W, float* __restrict__ part) {
  const int bx = blockIdx.x, t = threadIdx.x;
  float s0 = 0.f, s1 = 0.f, s2 = 0.f, s3 = 0.f;
#pragma unroll
  for (int r = 0; r < 16; ++r) {
    const float* row = W + (size_t)(bx * 16 + r) * Hn;
    s0 += row[t]; s1 += row[t + 256]; s2 += row[t + 512]; s3 += row[t + 768];
  }
  float* p = part + (size_t)bx * Hn;
  p[t] = s0; p[t + 256] = s1; p[t + 512] = s2; p[t + 768] = s3;
}

__global__ __launch_bounds__(256) void colsum_red(
    const float* __restrict__ part, float* __restrict__ cs) {
  const int col = blockIdx.x * 256 + threadIdx.x;
  float s = 0.f;
#pragma unroll
  for (int k = 0; k < 64; ++k) s += part[(size_t)k * Hn + col];
  cs[col] = s;
}

__global__ void bsum_k(const float* __restrict__ bvec, float* __restrict__ bs) {
  __shared__ float sb[4];
  float s = 0.f;
  for (int i = threadIdx.x; i < Vn; i += 256) s += bvec[i];
  for (int off = 32; off > 0; off >>= 1) s += __shfl_down(s, off, 64);
  int wv = threadIdx.x >> 6, ln = threadIdx.x & 63;
  if (ln == 0) sb[wv] = s;
  __syncthreads();
  if (threadIdx.x == 0) bs[0] = sb[0] + sb[1] + sb[2] + sb[3];
}

__global__ __launch_bounds__(256) void cast_W(
    const float* __restrict__ W, f16* __restrict__ Wf, f16* __restrict__ WTf) {
  __shared__ f16 tile[64][65];
  const int j0 = blockIdx.x * 64, i0 = blockIdx.y * 64;
  const int tx = threadIdx.x & 63, tg = threadIdx.x >> 6;
#pragma unroll 4
  for (int rr = 0; rr < 16; ++rr) {
    const int row = tg * 16 + rr;
    float w = W[(size_t)(i0 + row) * Hn + j0 + tx];
    f16 hw = (f16)w;
    Wf[(size_t)(i0 + row) * Hn + j0 + tx] = hw;
    tile[row][tx] = hw;
  }
  __syncthreads();
#pragma unroll 4
  for (int rr = 0; rr < 16; ++rr) {
    const int row = tg * 16 + rr;
    WTf[(size_t)(j0 + row) * Vn + i0 + tx] = tile[tx][row];
  }
}

__global__ void u0_init(const uint2* __restrict__ keys, float* __restrict__ u0) {
  int b = blockIdx.x * 256 + threadIdx.x;
  float r01 = rng_u01(keys[0], (uint32_t)b);
  u0[b] = (r01 < 0.5f) ? 1.f : 0.f;
}

// x0 = u0 ? v_data : 1-v_data; also emit pXB[0][row][slot] = Sum x0*b (32 cols)
__global__ __launch_bounds__(256) void cast_vx(
    const float* __restrict__ vd, const float* __restrict__ u0,
    const float* __restrict__ bvec, f16* __restrict__ x,
    float* __restrict__ pXB0) {
  const int row = blockIdx.x;                       // 1 row per block
  const int t = threadIdx.x;                        // cols 4t..4t+3
  const float uo = u0[row];
  const float4 d  = ((const float4*)(vd + (size_t)row * Vn))[t];
  const float4 bv = ((const float4*)bvec)[t];
  float xv[4] = { d.x, d.y, d.z, d.w };
  if (uo <= 0.5f) { xv[0]=1.f-xv[0]; xv[1]=1.f-xv[1]; xv[2]=1.f-xv[2]; xv[3]=1.f-xv[3]; }
  f16x4 o = { (f16)xv[0], (f16)xv[1], (f16)xv[2], (f16)xv[3] };
  *(f16x4*)(x + (size_t)row * Vn + t * 4) = o;
  float xb = xv[0]*bv.x + xv[1]*bv.y + xv[2]*bv.z + xv[3]*bv.w;
#pragma unroll
  for (int m = 1; m < 8; m <<= 1) xb += __shfl_xor(xb, m, 64);
  if ((t & 7) == 0) pXB0[(size_t)row * 32 + (t >> 3)] = xb;
}

// ---------- GEMM: 128x64 tile, 4 blocks/CU, XCD-placed, DPP epilogue --------
// Tile remap (T1): L=by*64+bx (hw linear id, XCD = L%8 round-robin);
// xcd=L&7, s=L>>3 -> bxp = xcd*8 + s/16, byp = s&15. Each XCD owns 8
// bx-panels x all 16 by: L2 set = 8x256KB(A) + 2MB(W) = 4MB.
// 4 waves in 2x2 grid over (128 rows x 64 cols); each wave owns 64x32 via
// acc[4][2] of 16x16x32. Per K-step: stage (4 A + 2 B loads), threefry 2
// samples, sync, [setprio(1)] ds_read+16 MFMA [setprio(0)], sync.
// Each wave covers exactly one 32-col slot: slot = byp*2 + (wave&1).
// EPI 1: h=Bern(sig(M+c)); pA = Sum h*colsum, pXA = Sum h*M per slot.
// EPI 2: EPI1 + free-energy partials SA = Sum sp(M+c), SB = Sum sp(cs-M+c).
// EPI 3: x_new=Bern(sig(C+b)); pXBn = Sum x_new*b per slot.
// EPI 4: SA/SB partials only (no RNG).
template <int EPI>
__global__ __launch_bounds__(256, 4) void gemm_s(
    const f16* __restrict__ A, const f16* __restrict__ Bm,
    f16* __restrict__ outH, f16* __restrict__ xnew,
    const float* __restrict__ bvec, const float* __restrict__ cvec,
    const float* __restrict__ colsum,
    float* __restrict__ pA, float* __restrict__ pXA, float* __restrict__ pXBn,
    float* __restrict__ pSA, float* __restrict__ pSB,
    const uint2* __restrict__ keys, int keyIdx)
{
  constexpr int N = 1024, K = 1024, BK = 64;
  __shared__ alignas(16) f16 As[128 * BK];   // 16 KB
  __shared__ alignas(16) f16 Bs[64 * BK];    // 8 KB

  const int t = threadIdx.x, wave = t >> 6, lane = t & 63;
  const int l15 = lane & 15, quad = lane >> 4;

  // T1 placement: bijective (bx,by) remap grouping A-panels per XCD
  const int L   = blockIdx.y * 64 + blockIdx.x;
  const int xcd = L & 7, sl = L >> 3;
  const int bxp = xcd * 8 + (sl >> 4);
  const int byp = sl & 15;
  const int m0 = bxp * 128, n0 = byp * 64;
  const int wm = (wave >> 1) * 64, wn = (wave & 1) * 32;

  const int rbase = lane >> 3;                 // row within an 8-row group
  const int gch   = (lane & 7) ^ rbase;        // pre-swizzled source chunk
  const f16* gA = A  + (size_t)(m0 + wave * 32 + rbase) * K + gch * 8;
  const f16* gB = Bm + (size_t)(n0 + wave * 16 + rbase) * K + gch * 8;
  f16* lA = As + wave * 32 * BK;
  f16* lB = Bs + wave * 16 * BK;

  const int swz = l15 & 7;
  const int oA  = (wm + l15) * BK;
  const int oB  = (wn + l15) * BK;

  uint2 key = make_uint2(0u, 0u);
  if constexpr (EPI != 4) key = keys[keyIdx];

  f32x4 acc[4][2] = {};
  float r01v[32];

#pragma unroll
  for (int ki = 0; ki < 16; ++ki) {
    const int k0 = ki * 64;
    // 1) stage K-tile ki (issue only; drained by the coming barrier)
#pragma unroll
    for (int i = 0; i < 4; ++i)
      GLOBAL_LOAD_LDS16(gA + k0 + i * 8 * K, lA + i * 8 * BK);
#pragma unroll
    for (int i = 0; i < 2; ++i)
      GLOBAL_LOAD_LDS16(gB + k0 + i * 8 * K, lB + i * 8 * BK);
    // 2) threefry for elements 2ki, 2ki+1 while loads fly (inlined)
    if constexpr (EPI != 4) {
      uint32_t idx[2];
#pragma unroll
      for (int j = 0; j < 2; ++j) {
        const int e  = ki * 2 + j;                  // e = mt*8 + r*2 + nt
        const int mt = e >> 3, r = (e >> 1) & 3, nt = e & 1;
        const int gm = m0 + wm + mt * 16 + quad * 4 + r;
        const int gn = n0 + wn + nt * 16 + l15;
        idx[j] = (uint32_t)(gm * N + gn);
      }
      float2 rv = rng2_u01(key, idx[0], idx[1]);
      r01v[ki * 2 + 0] = rv.x;
      r01v[ki * 2 + 1] = rv.y;
    }
    __syncthreads();
    // 3) compute on the staged tile (T5: favored by the CU scheduler)
    __builtin_amdgcn_s_setprio(1);
#pragma unroll
    for (int kc = 0; kc < 2; ++kc) {
      const int fc = ((kc * 4 + quad) ^ swz) * 8;
      f16x8 af[4], bf[2];
#pragma unroll
      for (int i = 0; i < 4; ++i)
        af[i] = *(const f16x8*)(&As[oA + i * 16 * BK + fc]);
#pragma unroll
      for (int i = 0; i < 2; ++i)
        bf[i] = *(const f16x8*)(&Bs[oB + i * 16 * BK + fc]);
#pragma unroll
      for (int mt = 0; mt < 4; ++mt)
#pragma unroll
        for (int nt = 0; nt < 2; ++nt)
          acc[mt][nt] = __builtin_amdgcn_mfma_f32_16x16x32_f16(af[mt], bf[nt], acc[mt][nt], 0, 0, 0);
    }
    __builtin_amdgcn_s_setprio(0);
    if (ki < 15) __syncthreads();
  }

  // epilogue: C/D layout col = lane&15, row = quad*4 + reg   (m89/m91)
  // each wave covers one 32-col slot
  const int slot = byp * 2 + (wave & 1);

  if constexpr (EPI == 1 || EPI == 2) {
    float csv[2], cvv[2];
#pragma unroll
    for (int nt = 0; nt < 2; ++nt) {
      const int gn = n0 + wn + nt * 16 + l15;
      csv[nt] = colsum[gn];
      cvv[nt] = cvec[gn];
    }
#pragma unroll
    for (int mt = 0; mt < 4; ++mt)
#pragma unroll
      for (int r = 0; r < 4; ++r) {
        const int gm = m0 + wm + mt * 16 + quad * 4 + r;
        float pa = 0.f, pxa = 0.f, sa = 0.f, sb = 0.f;
#pragma unroll
        for (int nt = 0; nt < 2; ++nt) {
          const int gn = n0 + wn + nt * 16 + l15;
          const float val = acc[mt][nt][r];            // M = x@W
          const float r01 = r01v[mt * 8 + r * 2 + nt];
          float hq  = bern_fast(val + cvv[nt], r01);
          outH[(size_t)gm * N + gn] = (f16)hq;
          pa  += hq * csv[nt];
          pxa += hq * val;
          if constexpr (EPI == 2) {
            sa += softplus_fast(val + cvv[nt]);
            sb += softplus_fast(csv[nt] - val + cvv[nt]);
          }
        }
        pa  = red16(pa);
        pxa = red16(pxa);
        if constexpr (EPI == 2) {
          sa = red16(sa);
          sb = red16(sb);
        }
        if (l15 == 0) {
          pA [(size_t)gm * 32 + slot] = pa;
          pXA[(size_t)gm * 32 + slot] = pxa;
          if constexpr (EPI == 2) {
            pSA[(size_t)gm * 32 + slot] = sa;
            pSB[(size_t)gm * 32 + slot] = sb;
          }
        }
      }
  } else if constexpr (EPI == 3) {
    float bb[2];
#pragma unroll
    for (int nt = 0; nt < 2; ++nt) bb[nt] = bvec[n0 + wn + nt * 16 + l15];
#pragma unroll
    for (int mt = 0; mt < 4; ++mt)
#pragma unroll
      for (int r = 0; r < 4; ++r) {
        const int gm = m0 + wm + mt * 16 + quad * 4 + r;
        float pxb = 0.f;
#pragma unroll
        for (int nt = 0; nt < 2; ++nt) {
          const int gn = n0 + wn + nt * 16 + l15;
          const float aval = acc[mt][nt][r];
          const float r01 = r01v[mt * 8 + r * 2 + nt];
          float xq  = bern_fast(aval + bb[nt], r01);
          xnew[(size_t)gm * N + gn] = (f16)xq;
          pxb += xq * bb[nt];
        }
        pxb = red16(pxb);
        if (l15 == 0) pXBn[(size_t)gm * 32 + slot] = pxb;
      }
  } else {
    // EPI 4: free-energy partials only
    float csv[2], cvv[2];
#pragma unroll
    for (int nt = 0; nt < 2; ++nt) {
      const int gn = n0 + wn + nt * 16 + l15;
      csv[nt] = colsum[gn];
      cvv[nt] = cvec[gn];
    }
#pragma unroll
    for (int mt = 0; mt < 4; ++mt)
#pragma unroll
      for (int r = 0; r < 4; ++r) {
        const int gm = m0 + wm + mt * 16 + quad * 4 + r;
        float sa = 0.f, sb = 0.f;
#pragma unroll
        for (int nt = 0; nt < 2; ++nt) {
          const float val = acc[mt][nt][r];
          sa += softplus_fast(val + cvv[nt]);
          sb += softplus_fast(csv[nt] - val + cvv[nt]);
        }
        sa = red16(sa);
        sb = red16(sb);
        if (l15 == 0) {
          pSA[(size_t)gm * 32 + slot] = sa;
          pSB[(size_t)gm * 32 + slot] = sb;
        }
      }
  }
}

// -------- deferred u-recurrence: half-wave per row, coalesced reads ---------
__global__ __launch_bounds__(256) void u_chain(
    const float* __restrict__ pA, const float* __restrict__ pXA,
    const float* __restrict__ pXB, const float* __restrict__ bsum,
    const uint2* __restrict__ keys, const float* __restrict__ u0,
    float* __restrict__ uF)
{
  const int t = threadIdx.x, wave = t >> 6, lane = t & 63;
  const int r2 = lane >> 5, slot = lane & 31;
  const int row = blockIdx.x * 8 + wave * 2 + r2;
  const float bs = bsum[0];
  float uo = u0[row];
  for (int s = 0; s < KSTEPS; ++s) {
    const size_t o = (size_t)s * 32 * Bn + (size_t)row * 32 + slot;
    float sa  = pA [o];
    float sxa = pXA[o];
    float sxb = pXB[o];
#pragma unroll
    for (int m = 1; m < 32; m <<= 1) {
      sa  += __shfl_xor(sa,  m, 64);
      sxa += __shfl_xor(sxa, m, 64);
      sxb += __shfl_xor(sxb, m, 64);
    }
    const float va = (uo > 0.5f) ? sxa : sa - sxa;
    const float vb = (uo > 0.5f) ? sxb : bs - sxb;
    const float dE = -bs - sa + 2.f * vb + 2.f * va;
    uo = bern_fast(dE, rng_u01(keys[2 + 3 * s], (uint32_t)row));
  }
  if (slot == 0) uF[row] = uo;
}

// ---------------- fused free energy finish (Fd and Fm) ----------------------
__device__ __forceinline__ float fe_eval(float SA, float SB, float xb,
                                         float uo, float bs) {
  float S1 = (uo > 0.5f) ? SA : SB;
  float S2 = (uo > 0.5f) ? SB : SA;
  float vb = (uo > 0.5f) ? xb : bs - xb;
  float negn = vb - S1;
  float negf = (bs - vb) - S2;
  float mx = fmaxf(negn, negf);
  return -(mx + logf(expf(negn - mx) + expf(negf - mx)));
}

__global__ __launch_bounds__(256) void fe_finish(
    const float* __restrict__ SA0, const float* __restrict__ SB0,
    const float* __restrict__ xb0,
    const float* __restrict__ SAF, const float* __restrict__ SBF,
    const float* __restrict__ xbF,
    const float* __restrict__ u0, const float* __restrict__ uF,
    const float* __restrict__ bsum,
    float* __restrict__ Fd, float* __restrict__ Fm)
{
  const int t = threadIdx.x, wave = t >> 6, lane = t & 63;
  const int r2 = lane >> 5, slot = lane & 31;
  const int row = blockIdx.x * 8 + wave * 2 + r2;
  const size_t o = (size_t)row * 32 + slot;
  const float bs = bsum[0];
  float a0 = SA0[o], b0 = SB0[o], x0 = xb0[o];
  float aF = SAF[o], bF = SBF[o], xF = xbF[o];
#pragma unroll
  for (int m = 1; m < 32; m <<= 1) {
    a0 += __shfl_xor(a0, m, 64);  b0 += __shfl_xor(b0, m, 64);
    x0 += __shfl_xor(x0, m, 64);  aF += __shfl_xor(aF, m, 64);
    bF += __shfl_xor(bF, m, 64);  xF += __shfl_xor(xF, m, 64);
  }
  if (slot == 0) {
    Fd[row] = fe_eval(a0, b0, x0, u0[row], bs);
    Fm[row] = fe_eval(aF, bF, xF, uF[row], bs);
  }
}

__global__ __launch_bounds__(256) void finalize_k(
    const float* __restrict__ Fd, const float* __restrict__ Fm, float* __restrict__ out)
{
  __shared__ double sb[8];
  double sd = 0.0, sm = 0.0;
  for (int i = threadIdx.x; i < Bn; i += 256) { sd += (double)Fd[i]; sm += (double)Fm[i]; }
  for (int off = 32; off > 0; off >>= 1) { sd += __shfl_down(sd, off, 64); sm += __shfl_down(sm, off, 64); }
  const int wv = threadIdx.x >> 6, ln = threadIdx.x & 63;
  if (ln == 0) { sb[wv] = sd; sb[4 + wv] = sm; }
  __syncthreads();
  if (threadIdx.x == 0) {
    sd = sb[0] + sb[1] + sb[2] + sb[3];
    sm = sb[4] + sb[5] + sb[6] + sb[7];
    out[0] = (float)((sd - sm) / (double)Bn);
  }
}

// ------------------------------ launch glue --------------------------------
extern "C" void kernel_launch(void* const* d_in, const int* in_sizes, int n_in,
                              void* d_out, int out_size, void* d_ws, size_t ws_size,
                              hipStream_t stream) {
  const float* v_data = (const float*)d_in[0];
  const float* W      = (const float*)d_in[1];
  const float* bvec   = (const float*)d_in[2];
  const float* cvec   = (const float*)d_in[3];
  const int*   seedp  = (const int*)d_in[4];
  float* out = (float*)d_out;

  char* ws = (char*)d_ws;
  size_t off = 0;
  auto alloc = [&](size_t bytes) -> void* {
    void* p = ws + off;
    off += (bytes + 255) & ~(size_t)255;
    return p;
  };
  f16*   xb0  = (f16*)alloc((size_t)Bn * Vn * 2);     // 16 MB x ping
  f16*   xb1  = (f16*)alloc((size_t)Bn * Vn * 2);     // 16 MB x pong
  f16*   h    = (f16*)alloc((size_t)Bn * Hn * 2);     // 16 MB
  f16*   Wf   = (f16*)alloc((size_t)Vn * Hn * 2);     // 2 MB  [V][H]
  f16*   WTf  = (f16*)alloc((size_t)Vn * Hn * 2);     // 2 MB  [H][V]
  float* cpart  = (float*)alloc(64 * Hn * 4);
  float* colsum = (float*)alloc(Hn * 4);
  float* bsum   = (float*)alloc(256);
  uint2* keys   = (uint2*)alloc(64 * sizeof(uint2));
  float* u0     = (float*)alloc(Bn * 4);
  float* uF     = (float*)alloc(Bn * 4);
  float* pA     = (float*)alloc((size_t)KSTEPS * 32 * Bn * 4);        // 10 MB
  float* pXA    = (float*)alloc((size_t)KSTEPS * 32 * Bn * 4);        // 10 MB
  float* pXB    = (float*)alloc((size_t)(KSTEPS + 1) * 32 * Bn * 4);  // 11 MB
  float* SA0    = (float*)alloc((size_t)32 * Bn * 4);                 // 1 MB
  float* SB0    = (float*)alloc((size_t)32 * Bn * 4);
  float* SAF    = (float*)alloc((size_t)32 * Bn * 4);
  float* SBF    = (float*)alloc((size_t)32 * Bn * 4);
  float* Fd     = (float*)alloc(Bn * 4);
  float* Fm     = (float*)alloc(Bn * 4);
  (void)ws_size; (void)in_sizes; (void)n_in; (void)out_size;

  prep_keys<<<1, 64, 0, stream>>>(seedp, keys);
  colsum_part<<<64, 256, 0, stream>>>(W, cpart);
  colsum_red<<<4, 256, 0, stream>>>(cpart, colsum);
  bsum_k<<<1, 256, 0, stream>>>(bvec, bsum);
  cast_W<<<dim3(Hn / 64, Vn / 64), 256, 0, stream>>>(W, Wf, WTf);
  u0_init<<<Bn / 256, 256, 0, stream>>>(keys, u0);
  cast_vx<<<Bn, 256, 0, stream>>>(v_data, u0, bvec, xb0, pXB);   // pXB slab 0

  dim3 gg(Bn / 128, Hn / 64);   // 1024 blocks = 4/CU (tile remapped in-kernel)
  f16* xs[2] = { xb0, xb1 };
  const size_t SL = (size_t)32 * Bn;

  for (int s = 0; s < KSTEPS; ++s) {
    // M = x_s@W -> h sampled; pA/pXA slab s; step 0 also emits SA0/SB0 (Fd)
    if (s == 0) {
      gemm_s<2><<<gg, 256, 0, stream>>>(xs[0], WTf, h, nullptr, nullptr, cvec,
                                        colsum, pA, pXA, nullptr, SA0, SB0,
                                        keys, 1);
    } else {
      gemm_s<1><<<gg, 256, 0, stream>>>(xs[s & 1], WTf, h, nullptr, nullptr, cvec,
                                        colsum, pA + (size_t)s * SL,
                                        pXA + (size_t)s * SL, nullptr,
                                        nullptr, nullptr, keys, 1 + 3 * s);
    }
    // a = h@W^T -> x_{s+1} sampled; pXB slab s+1
    gemm_s<3><<<gg, 256, 0, stream>>>(h, Wf, nullptr, xs[(s + 1) & 1], bvec,
                                      nullptr, nullptr, nullptr, nullptr,
                                      pXB + (size_t)(s + 1) * SL,
                                      nullptr, nullptr, keys, 3 + 3 * s);
  }

  // F(v_model) partials: M = x10@W -> SAF/SBF
  gemm_s<4><<<gg, 256, 0, stream>>>(xs[KSTEPS & 1], WTf, nullptr, nullptr,
                                    nullptr, cvec, colsum, nullptr, nullptr,
                                    nullptr, SAF, SBF, keys, 0);

  u_chain<<<Bn / 8, 256, 0, stream>>>(pA, pXA, pXB, bsum, keys, u0, uF);
  fe_finish<<<Bn / 8, 256, 0, stream>>>(SA0, SB0, pXB,
                                        SAF, SBF, pXB + (size_t)KSTEPS * SL,
                                        u0, uF, bsum, Fd, Fm);
  finalize_k<<<1, 256, 0, stream>>>(Fd, Fm, out);
}